// Round 2
// baseline (241.424 us; speedup 1.0000x reference)
//
#include <hip/hip_runtime.h>

typedef __bf16 bf16x8 __attribute__((ext_vector_type(8)));
typedef float f32x4 __attribute__((ext_vector_type(4)));
typedef unsigned short ushort8 __attribute__((ext_vector_type(8)));

#define C_DIM 512
#define N_DIM 4096
#define NBATCH 16

// ---------- helpers ----------

__device__ __forceinline__ unsigned short f2bf(float f) {
  unsigned int u = __builtin_bit_cast(unsigned int, f);
  u += 0x7FFFu + ((u >> 16) & 1u);
  return (unsigned short)(u >> 16);
}

__device__ __forceinline__ void gload_lds16(const void* g, void* l) {
  __builtin_amdgcn_global_load_lds(
      (const __attribute__((address_space(1))) void*)g,
      (__attribute__((address_space(3))) void*)l, 16, 0, 0);
}

// ---------- 1) cast x (fp32) -> q (bf16) ----------

__global__ __launch_bounds__(256) void cast_kernel(
    const float* __restrict__ x, unsigned short* __restrict__ q, long n8) {
  long stride = (long)gridDim.x * blockDim.x;
  for (long i = (long)blockIdx.x * blockDim.x + threadIdx.x; i < n8; i += stride) {
    const float4* xv = reinterpret_cast<const float4*>(x) + i * 2;
    float4 a = xv[0];
    float4 b = xv[1];
    ushort8 o;
    o[0] = f2bf(a.x); o[1] = f2bf(a.y); o[2] = f2bf(a.z); o[3] = f2bf(a.w);
    o[4] = f2bf(b.x); o[5] = f2bf(b.y); o[6] = f2bf(b.z); o[7] = f2bf(b.w);
    reinterpret_cast<ushort8*>(q)[i] = o;
  }
}

// ---------- 2) energy[b] += q[b] @ q[b]^T  (NT GEMM, split-K x2, swizzled LDS) ----------
// grid: 16 batches * 4 tr * 4 tc * 2 ksplit = 512 blocks, 256 threads.
// LDS tiles [128][64] ushort, 16B-chunk XOR swizzle: phys chunk j' holds logical
// chunk j = j' ^ (row&7)  (linear global_load_lds dest + pre-swizzled source).

__global__ __launch_bounds__(256) void gemm_qqt(
    const unsigned short* __restrict__ q, float* __restrict__ energy) {
  const int K = N_DIM;
  int bidx = blockIdx.x;
  int ks = bidx & 1;
  int tc = (bidx >> 1) & 3;
  int tr = (bidx >> 3) & 3;
  int b  = bidx >> 5;
  const unsigned short* Abase = q + (size_t)(b * C_DIM + tr * 128) * K;
  const unsigned short* Bbase = q + (size_t)(b * C_DIM + tc * 128) * K;
  float* Cp = energy + (size_t)b * C_DIM * C_DIM;

  __shared__ __align__(16) unsigned short As[128 * 64];
  __shared__ __align__(16) unsigned short Bs[128 * 64];

  int t = threadIdx.x;
  int lane = t & 63;
  int w = t >> 6;
  int wr = w >> 1, wc = w & 1;

  f32x4 acc[4][4] = {};

  int k0beg = ks * (K / 2);
  for (int k0 = k0beg; k0 < k0beg + K / 2; k0 += 64) {
    // stage: 1024 chunks of 16B per tile; chunk c -> row=c>>3, phys j'=c&7,
    // source column = (j' ^ (row&7))*8 (inverse swizzle on the global side)
#pragma unroll
    for (int i = 0; i < 4; ++i) {
      int c = i * 256 + t;
      int row = c >> 3, jp = c & 7;
      int scol = ((jp ^ (row & 7)) * 8);
      gload_lds16(Abase + (size_t)row * K + k0 + scol, As + c * 8);
      gload_lds16(Bbase + (size_t)row * K + k0 + scol, Bs + c * 8);
    }
    __syncthreads();
#pragma unroll
    for (int kk = 0; kk < 2; ++kk) {
      bf16x8 af[4], bfr[4];
#pragma unroll
      for (int mi = 0; mi < 4; ++mi) {
        int row = wr * 64 + mi * 16 + (lane & 15);
        int ch = (kk * 4 + (lane >> 4)) ^ (row & 7);
        af[mi] = *reinterpret_cast<const bf16x8*>(As + row * 64 + ch * 8);
      }
#pragma unroll
      for (int ni = 0; ni < 4; ++ni) {
        int row = wc * 64 + ni * 16 + (lane & 15);
        int ch = (kk * 4 + (lane >> 4)) ^ (row & 7);
        bfr[ni] = *reinterpret_cast<const bf16x8*>(Bs + row * 64 + ch * 8);
      }
#pragma unroll
      for (int mi = 0; mi < 4; ++mi)
#pragma unroll
        for (int ni = 0; ni < 4; ++ni)
          acc[mi][ni] = __builtin_amdgcn_mfma_f32_16x16x32_bf16(
              af[mi], bfr[ni], acc[mi][ni], 0, 0, 0);
    }
    __syncthreads();
  }

  int r0 = tr * 128 + wr * 64;
  int c0 = tc * 128 + wc * 64;
#pragma unroll
  for (int mi = 0; mi < 4; ++mi)
#pragma unroll
    for (int ni = 0; ni < 4; ++ni)
#pragma unroll
      for (int r = 0; r < 4; ++r) {
        int row = r0 + mi * 16 + (lane >> 4) * 4 + r;
        int col = c0 + ni * 16 + (lane & 15);
        atomicAdd(&Cp[(size_t)row * C_DIM + col], acc[mi][ni][r]);
      }
}

// ---------- 3) att = softmax(min_row(e) - e) rowwise, write bf16 ----------

__global__ __launch_bounds__(256) void softmax_rows(
    const float* __restrict__ energy, unsigned short* __restrict__ att) {
  int w = threadIdx.x >> 6;
  int lane = threadIdx.x & 63;
  int row = blockIdx.x * 4 + w;
  const float* e = energy + (size_t)row * C_DIM;
  unsigned short* a = att + (size_t)row * C_DIM;
  float v[8];
  float mn = 3.0e38f;
#pragma unroll
  for (int j = 0; j < 8; ++j) {
    v[j] = e[j * 64 + lane];
    mn = fminf(mn, v[j]);
  }
#pragma unroll
  for (int s = 32; s >= 1; s >>= 1) mn = fminf(mn, __shfl_xor(mn, s));
  float p[8];
  float sum = 0.f;
#pragma unroll
  for (int j = 0; j < 8; ++j) {
    p[j] = __expf(mn - v[j]);
    sum += p[j];
  }
#pragma unroll
  for (int s = 32; s >= 1; s >>= 1) sum += __shfl_xor(sum, s);
  float inv = 1.0f / sum;
#pragma unroll
  for (int j = 0; j < 8; ++j) a[j * 64 + lane] = f2bf(p[j] * inv);
}

// ---------- 4) out = gamma * (att @ q) + x ----------
// A (att, 8.4MB, L2/L3-resident) read DIRECT from global as k-contiguous bf16x8
// fragments — no LDS tile, no bank conflicts. B (q) transpose-staged via regs
// into padded LDS [128][72] (conflict-free writes and reads).

__global__ __launch_bounds__(256) void gemm_av(
    const unsigned short* __restrict__ att, const unsigned short* __restrict__ q,
    const float* __restrict__ x, const float* __restrict__ gamma,
    float* __restrict__ out) {
  int bidx = blockIdx.x;
  int b  = bidx >> 7;
  int tr = (bidx >> 5) & 3;
  int tc = bidx & 31;

  const unsigned short* Abase = att + (size_t)(b * C_DIM + tr * 128) * C_DIM;
  const unsigned short* qb = q + (size_t)b * C_DIM * N_DIM;

  __shared__ __align__(16) unsigned short Bs[128][72];

  int t = threadIdx.x;
  int lane = t & 63;
  int w = t >> 6;
  int wr = w >> 1, wc = w & 1;

  f32x4 acc[4][4] = {};

  for (int k0 = 0; k0 < C_DIM; k0 += 64) {
    // B tile transpose-stage: q[k0+d][n0+n] -> Bs[n][d]
#pragma unroll
    for (int i = 0; i < 2; ++i) {
      int u = i * 256 + t;
      int dp = u & 31;
      int oct = u >> 5;
      int d = dp * 2;
      int n = oct * 8;
      const unsigned short* src = qb + (size_t)(k0 + d) * N_DIM + tc * 128 + n;
      ushort8 rA = *reinterpret_cast<const ushort8*>(src);
      ushort8 rB = *reinterpret_cast<const ushort8*>(src + N_DIM);
#pragma unroll
      for (int m = 0; m < 8; ++m) {
        unsigned int val = (unsigned int)rA[m] | ((unsigned int)rB[m] << 16);
        *reinterpret_cast<unsigned int*>(&Bs[n + m][d]) = val;
      }
    }
    __syncthreads();
#pragma unroll
    for (int kk = 0; kk < 2; ++kk) {
      bf16x8 af[4], bfr[4];
#pragma unroll
      for (int mi = 0; mi < 4; ++mi) {
        int row = wr * 64 + mi * 16 + (lane & 15);
        af[mi] = *reinterpret_cast<const bf16x8*>(
            Abase + (size_t)row * C_DIM + k0 + kk * 32 + (lane >> 4) * 8);
      }
#pragma unroll
      for (int ni = 0; ni < 4; ++ni)
        bfr[ni] = *reinterpret_cast<const bf16x8*>(
            &Bs[wc * 64 + ni * 16 + (lane & 15)][kk * 32 + (lane >> 4) * 8]);
#pragma unroll
      for (int mi = 0; mi < 4; ++mi)
#pragma unroll
        for (int ni = 0; ni < 4; ++ni)
          acc[mi][ni] = __builtin_amdgcn_mfma_f32_16x16x32_bf16(
              af[mi], bfr[ni], acc[mi][ni], 0, 0, 0);
    }
    __syncthreads();
  }

  float g = gamma[0];
  const float* xb = x + (size_t)b * C_DIM * N_DIM;
  float* ob = out + (size_t)b * C_DIM * N_DIM;
  int r0 = tr * 128 + wr * 64;
  int n0 = tc * 128 + wc * 64;
#pragma unroll
  for (int mi = 0; mi < 4; ++mi)
#pragma unroll
    for (int ni = 0; ni < 4; ++ni)
#pragma unroll
      for (int r = 0; r < 4; ++r) {
        int row = r0 + mi * 16 + (lane >> 4) * 4 + r;
        int col = n0 + ni * 16 + (lane & 15);
        size_t idx = (size_t)row * N_DIM + col;
        ob[idx] = fmaf(g, acc[mi][ni][r], xb[idx]);
      }
}

// ---------- launch ----------

extern "C" void kernel_launch(void* const* d_in, const int* in_sizes, int n_in,
                              void* d_out, int out_size, void* d_ws, size_t ws_size,
                              hipStream_t stream) {
  const float* x = (const float*)d_in[0];
  const float* gamma = (const float*)d_in[1];
  float* out = (float*)d_out;

  // workspace layout (total 92,274,688 B):
  //   q      bf16 [16][512][4096]  67,108,864 B
  //   energy f32  [16][512][512]   16,777,216 B
  //   att    bf16 [16][512][512]    8,388,608 B
  char* ws = (char*)d_ws;
  unsigned short* q = (unsigned short*)ws;
  float* energy = (float*)(ws + 67108864);
  unsigned short* att = (unsigned short*)(ws + 67108864 + 16777216);

  long n8 = (long)NBATCH * C_DIM * N_DIM / 8;
  hipMemsetAsync(energy, 0, (size_t)NBATCH * C_DIM * C_DIM * 4, stream);
  cast_kernel<<<2048, 256, 0, stream>>>(x, q, n8);
  gemm_qqt<<<512, 256, 0, stream>>>(q, energy);
  softmax_rows<<<2048, 256, 0, stream>>>(energy, att);
  gemm_av<<<2048, 256, 0, stream>>>(att, q, x, gamma, out);
}

// Round 3
// 200.181 us; speedup vs baseline: 1.2060x; 1.2060x over previous
//
#include <hip/hip_runtime.h>

typedef __bf16 bf16x8 __attribute__((ext_vector_type(8)));
typedef float f32x4 __attribute__((ext_vector_type(4)));
typedef unsigned short ushort8 __attribute__((ext_vector_type(8)));

#define C_DIM 512
#define N_DIM 4096
#define NBATCH 16

// ---------- helpers ----------

__device__ __forceinline__ unsigned short f2bf(float f) {
  unsigned int u = __builtin_bit_cast(unsigned int, f);
  u += 0x7FFFu + ((u >> 16) & 1u);
  return (unsigned short)(u >> 16);
}

__device__ __forceinline__ void gload_lds16(const void* g, void* l) {
  __builtin_amdgcn_global_load_lds(
      (const __attribute__((address_space(1))) void*)g,
      (__attribute__((address_space(3))) void*)l, 16, 0, 0);
}

// ---------- 1) cast x (fp32) -> q (bf16) ----------

__global__ __launch_bounds__(256) void cast_kernel(
    const float* __restrict__ x, unsigned short* __restrict__ q, long n8) {
  long stride = (long)gridDim.x * blockDim.x;
  for (long i = (long)blockIdx.x * blockDim.x + threadIdx.x; i < n8; i += stride) {
    const float4* xv = reinterpret_cast<const float4*>(x) + i * 2;
    float4 a = xv[0];
    float4 b = xv[1];
    ushort8 o;
    o[0] = f2bf(a.x); o[1] = f2bf(a.y); o[2] = f2bf(a.z); o[3] = f2bf(a.w);
    o[4] = f2bf(b.x); o[5] = f2bf(b.y); o[6] = f2bf(b.z); o[7] = f2bf(b.w);
    reinterpret_cast<ushort8*>(q)[i] = o;
  }
}

// ---------- 2) energy[b] += q[b] @ q[b]^T  (NT GEMM, split-K x2, swizzled LDS) ----------
// grid: 16 batches * 4 tr * 4 tc * 2 ksplit = 512 blocks, 256 threads.
// LDS tiles [128][64] ushort, 16B-chunk XOR swizzle: phys chunk j' = j ^ (row&7)
// (linear global_load_lds dest + pre-swizzled source + swizzled read).

__global__ __launch_bounds__(256) void gemm_qqt(
    const unsigned short* __restrict__ q, float* __restrict__ energy) {
  const int K = N_DIM;
  int bidx = blockIdx.x;
  int ks = bidx & 1;
  int tc = (bidx >> 1) & 3;
  int tr = (bidx >> 3) & 3;
  int b  = bidx >> 5;
  const unsigned short* Abase = q + (size_t)(b * C_DIM + tr * 128) * K;
  const unsigned short* Bbase = q + (size_t)(b * C_DIM + tc * 128) * K;
  float* Cp = energy + (size_t)b * C_DIM * C_DIM;

  __shared__ __align__(16) unsigned short As[128 * 64];
  __shared__ __align__(16) unsigned short Bs[128 * 64];

  int t = threadIdx.x;
  int lane = t & 63;
  int w = t >> 6;
  int wr = w >> 1, wc = w & 1;

  f32x4 acc[4][4] = {};

  int k0beg = ks * (K / 2);
  for (int k0 = k0beg; k0 < k0beg + K / 2; k0 += 64) {
#pragma unroll
    for (int i = 0; i < 4; ++i) {
      int c = i * 256 + t;
      int row = c >> 3, jp = c & 7;
      int scol = ((jp ^ (row & 7)) * 8);
      gload_lds16(Abase + (size_t)row * K + k0 + scol, As + c * 8);
      gload_lds16(Bbase + (size_t)row * K + k0 + scol, Bs + c * 8);
    }
    __syncthreads();
#pragma unroll
    for (int kk = 0; kk < 2; ++kk) {
      bf16x8 af[4], bfr[4];
#pragma unroll
      for (int mi = 0; mi < 4; ++mi) {
        int row = wr * 64 + mi * 16 + (lane & 15);
        int ch = (kk * 4 + (lane >> 4)) ^ (row & 7);
        af[mi] = *reinterpret_cast<const bf16x8*>(As + row * 64 + ch * 8);
      }
#pragma unroll
      for (int ni = 0; ni < 4; ++ni) {
        int row = wc * 64 + ni * 16 + (lane & 15);
        int ch = (kk * 4 + (lane >> 4)) ^ (row & 7);
        bfr[ni] = *reinterpret_cast<const bf16x8*>(Bs + row * 64 + ch * 8);
      }
#pragma unroll
      for (int mi = 0; mi < 4; ++mi)
#pragma unroll
        for (int ni = 0; ni < 4; ++ni)
          acc[mi][ni] = __builtin_amdgcn_mfma_f32_16x16x32_bf16(
              af[mi], bfr[ni], acc[mi][ni], 0, 0, 0);
    }
    __syncthreads();
  }

  int r0 = tr * 128 + wr * 64;
  int c0 = tc * 128 + wc * 64;
#pragma unroll
  for (int mi = 0; mi < 4; ++mi)
#pragma unroll
    for (int ni = 0; ni < 4; ++ni)
#pragma unroll
      for (int r = 0; r < 4; ++r) {
        int row = r0 + mi * 16 + (lane >> 4) * 4 + r;
        int col = c0 + ni * 16 + (lane & 15);
        atomicAdd(&Cp[(size_t)row * C_DIM + col], acc[mi][ni][r]);
      }
}

// ---------- 3) att = softmax(min_row(e) - e) rowwise, write bf16 ----------

__global__ __launch_bounds__(256) void softmax_rows(
    const float* __restrict__ energy, unsigned short* __restrict__ att) {
  int w = threadIdx.x >> 6;
  int lane = threadIdx.x & 63;
  int row = blockIdx.x * 4 + w;
  const float* e = energy + (size_t)row * C_DIM;
  unsigned short* a = att + (size_t)row * C_DIM;
  float v[8];
  float mn = 3.0e38f;
#pragma unroll
  for (int j = 0; j < 8; ++j) {
    v[j] = e[j * 64 + lane];
    mn = fminf(mn, v[j]);
  }
#pragma unroll
  for (int s = 32; s >= 1; s >>= 1) mn = fminf(mn, __shfl_xor(mn, s));
  float p[8];
  float sum = 0.f;
#pragma unroll
  for (int j = 0; j < 8; ++j) {
    p[j] = __expf(mn - v[j]);
    sum += p[j];
  }
#pragma unroll
  for (int s = 32; s >= 1; s >>= 1) sum += __shfl_xor(sum, s);
  float inv = 1.0f / sum;
#pragma unroll
  for (int j = 0; j < 8; ++j) a[j * 64 + lane] = f2bf(p[j] * inv);
}

// ---------- 4) out = gamma * (att @ q) + x ----------
// A (att) staged via global_load_lds with XOR-chunk swizzle (conflict-free
// b128 reads). B (q) transpose-staged via regs into padded LDS [128][72].

__global__ __launch_bounds__(256) void gemm_av(
    const unsigned short* __restrict__ att, const unsigned short* __restrict__ q,
    const float* __restrict__ x, const float* __restrict__ gamma,
    float* __restrict__ out) {
  int bidx = blockIdx.x;
  int b  = bidx >> 7;
  int tr = (bidx >> 5) & 3;
  int tc = bidx & 31;

  const unsigned short* Abase = att + (size_t)(b * C_DIM + tr * 128) * C_DIM;
  const unsigned short* qb = q + (size_t)b * C_DIM * N_DIM;

  __shared__ __align__(16) unsigned short As[128 * 64];
  __shared__ __align__(16) unsigned short Bs[128][72];

  int t = threadIdx.x;
  int lane = t & 63;
  int w = t >> 6;
  int wr = w >> 1, wc = w & 1;

  f32x4 acc[4][4] = {};

  for (int k0 = 0; k0 < C_DIM; k0 += 64) {
    // A tile: att rows (lda = 512), swizzled stage
#pragma unroll
    for (int i = 0; i < 4; ++i) {
      int c = i * 256 + t;
      int row = c >> 3, jp = c & 7;
      int scol = ((jp ^ (row & 7)) * 8);
      gload_lds16(Abase + (size_t)row * C_DIM + k0 + scol, As + c * 8);
    }
    // B tile transpose-stage: q[k0+d][n0+n] -> Bs[n][d]
#pragma unroll
    for (int i = 0; i < 2; ++i) {
      int u = i * 256 + t;
      int dp = u & 31;
      int oct = u >> 5;
      int d = dp * 2;
      int n = oct * 8;
      const unsigned short* src = qb + (size_t)(k0 + d) * N_DIM + tc * 128 + n;
      ushort8 rA = *reinterpret_cast<const ushort8*>(src);
      ushort8 rB = *reinterpret_cast<const ushort8*>(src + N_DIM);
#pragma unroll
      for (int m = 0; m < 8; ++m) {
        unsigned int val = (unsigned int)rA[m] | ((unsigned int)rB[m] << 16);
        *reinterpret_cast<unsigned int*>(&Bs[n + m][d]) = val;
      }
    }
    __syncthreads();
#pragma unroll
    for (int kk = 0; kk < 2; ++kk) {
      bf16x8 af[4], bfr[4];
#pragma unroll
      for (int mi = 0; mi < 4; ++mi) {
        int row = wr * 64 + mi * 16 + (lane & 15);
        int ch = (kk * 4 + (lane >> 4)) ^ (row & 7);
        af[mi] = *reinterpret_cast<const bf16x8*>(As + row * 64 + ch * 8);
      }
#pragma unroll
      for (int ni = 0; ni < 4; ++ni)
        bfr[ni] = *reinterpret_cast<const bf16x8*>(
            &Bs[wc * 64 + ni * 16 + (lane & 15)][kk * 32 + (lane >> 4) * 8]);
#pragma unroll
      for (int mi = 0; mi < 4; ++mi)
#pragma unroll
        for (int ni = 0; ni < 4; ++ni)
          acc[mi][ni] = __builtin_amdgcn_mfma_f32_16x16x32_bf16(
              af[mi], bfr[ni], acc[mi][ni], 0, 0, 0);
    }
    __syncthreads();
  }

  float g = gamma[0];
  const float* xb = x + (size_t)b * C_DIM * N_DIM;
  float* ob = out + (size_t)b * C_DIM * N_DIM;
  int r0 = tr * 128 + wr * 64;
  int n0 = tc * 128 + wc * 64;
#pragma unroll
  for (int mi = 0; mi < 4; ++mi)
#pragma unroll
    for (int ni = 0; ni < 4; ++ni)
#pragma unroll
      for (int r = 0; r < 4; ++r) {
        int row = r0 + mi * 16 + (lane >> 4) * 4 + r;
        int col = n0 + ni * 16 + (lane & 15);
        size_t idx = (size_t)row * N_DIM + col;
        ob[idx] = fmaf(g, acc[mi][ni][r], xb[idx]);
      }
}

// ---------- launch ----------

extern "C" void kernel_launch(void* const* d_in, const int* in_sizes, int n_in,
                              void* d_out, int out_size, void* d_ws, size_t ws_size,
                              hipStream_t stream) {
  const float* x = (const float*)d_in[0];
  const float* gamma = (const float*)d_in[1];
  float* out = (float*)d_out;

  // workspace layout (total 92,274,688 B):
  //   q      bf16 [16][512][4096]  67,108,864 B
  //   energy f32  [16][512][512]   16,777,216 B
  //   att    bf16 [16][512][512]    8,388,608 B
  char* ws = (char*)d_ws;
  unsigned short* q = (unsigned short*)ws;
  float* energy = (float*)(ws + 67108864);
  unsigned short* att = (unsigned short*)(ws + 67108864 + 16777216);

  long n8 = (long)NBATCH * C_DIM * N_DIM / 8;
  hipMemsetAsync(energy, 0, (size_t)NBATCH * C_DIM * C_DIM * 4, stream);
  cast_kernel<<<2048, 256, 0, stream>>>(x, q, n8);
  gemm_qqt<<<512, 256, 0, stream>>>(q, energy);
  softmax_rows<<<2048, 256, 0, stream>>>(energy, att);
  gemm_av<<<2048, 256, 0, stream>>>(att, q, x, gamma, out);
}